// Round 3
// baseline (257.691 us; speedup 1.0000x reference)
//
#include <hip/hip_runtime.h>

#define D 128

typedef __attribute__((ext_vector_type(8))) short short8;
typedef __attribute__((ext_vector_type(4))) float f32x4;

typedef __attribute__((address_space(3))) unsigned int lds_u32_t;
typedef const __attribute__((address_space(1))) unsigned int glb_u32_t;

static __device__ __forceinline__ unsigned short f2bf(float f) {
    unsigned int u = __float_as_uint(f);
    unsigned int r = (u + 0x7fffu + ((u >> 16) & 1u)) >> 16;
    return (unsigned short)r;
}
static __device__ __forceinline__ float bf_lo(unsigned int u) {
    return __uint_as_float(u << 16);
}
static __device__ __forceinline__ float bf_hi(unsigned int u) {
    return __uint_as_float(u & 0xffff0000u);
}
static __device__ __forceinline__ unsigned int pack2(float lo, float hi) {
    return (unsigned int)f2bf(lo) | ((unsigned int)f2bf(hi) << 16);
}

// ---------------- prep: convert W (blocks 0..31), convert x + zero cnt (rest) ----------------

__global__ void prep_kernel(const float* __restrict__ x, unsigned short* __restrict__ xb,
                            int total8,
                            const float* __restrict__ W0, const float* __restrict__ W1,
                            const float* __restrict__ W2, const float* __restrict__ W3,
                            unsigned short* __restrict__ wt,
                            int* __restrict__ cnt, int N) {
    int bx = blockIdx.x;
    int t = threadIdx.x;
    if (bx < 32) {
        // W [128k][128n] fp32 -> wt bf16 [m][n][chunk-swizzled k]:
        // chunk c stored at slot c ^ (n & 15)
        int tid = bx * 256 + t;            // 0..8191
        int m = tid >> 11;
        const float* W = (m == 0) ? W0 : (m == 1) ? W1 : (m == 2) ? W2 : W3;
        int r = tid & 2047;
        int n = r >> 4;
        int c = r & 15;
        float f[8];
#pragma unroll
        for (int i = 0; i < 8; ++i) f[i] = W[(size_t)(c * 8 + i) * 128 + n];
        uint4 o;
        o.x = pack2(f[0], f[1]);
        o.y = pack2(f[2], f[3]);
        o.z = pack2(f[4], f[5]);
        o.w = pack2(f[6], f[7]);
        *reinterpret_cast<uint4*>(wt + (size_t)m * 16384 + n * 128 + (c ^ (n & 15)) * 8) = o;
    } else {
        int i = (bx - 32) * 256 + t;
        if (i < N) cnt[i] = 0;
        if (i < total8) {
            const float4 v0 = *reinterpret_cast<const float4*>(x + (size_t)i * 8);
            const float4 v1 = *reinterpret_cast<const float4*>(x + (size_t)i * 8 + 4);
            uint4 o;
            o.x = pack2(v0.x, v0.y);
            o.y = pack2(v0.z, v0.w);
            o.z = pack2(v1.x, v1.y);
            o.w = pack2(v1.z, v1.w);
            *reinterpret_cast<uint4*>(xb + (size_t)i * 8) = o;
        }
    }
}

// ---------------- CSR build ----------------

__global__ void count_deg_kernel(const int* __restrict__ dst, int* __restrict__ cnt, int E) {
    int e = blockIdx.x * 256 + threadIdx.x;
    if (e < E) atomicAdd(&cnt[dst[e]], 1);
}

// single-block exclusive scan over N counts -> rowptr, cursor
__global__ void scan_all_kernel(const int* __restrict__ cnt, int* __restrict__ rowptr,
                                int* __restrict__ cursor, int N, int E) {
    __shared__ int tmp[1024];
    int t = threadIdx.x;
    int C = (N + 1023) >> 10;
    int beg = t * C;
    int end = beg + C < N ? beg + C : N;
    int s = 0;
    for (int i = beg; i < end; ++i) s += cnt[i];
    tmp[t] = s;
    __syncthreads();
    for (int off = 1; off < 1024; off <<= 1) {
        int v = (t >= off) ? tmp[t - off] : 0;
        __syncthreads();
        tmp[t] += v;
        __syncthreads();
    }
    int base = tmp[t] - s;    // exclusive prefix
    for (int i = beg; i < end; ++i) {
        int c = cnt[i];
        rowptr[i] = base;
        cursor[i] = base;
        base += c;
    }
    if (t == 0) rowptr[N] = E;
}

__global__ void fill_kernel(const int* __restrict__ src, const int* __restrict__ dst,
                            int* __restrict__ cursor, int* __restrict__ ssrc, int E) {
    int e = blockIdx.x * 256 + threadIdx.x;
    if (e < E) {
        int d = dst[e];
        int pos = atomicAdd(&cursor[d], 1);
        ssrc[pos] = src[e];
    }
}

// ---------------- mean aggregation (bf16 in, bf16 out, fp32 accum) ----------------
// one wave per node; quarter-waves process 4 edges concurrently; 16 lanes cover 128 elems

__global__ void agg_kernel(const unsigned short* __restrict__ feat, const int* __restrict__ rowptr,
                           const int* __restrict__ ssrc, unsigned short* __restrict__ out, int N) {
    int w = (blockIdx.x * blockDim.x + threadIdx.x) >> 6;
    if (w >= N) return;
    int lane = threadIdx.x & 63;
    int q = lane >> 4;
    int l15 = lane & 15;
    int beg = rowptr[w], end = rowptr[w + 1];
    float acc[8] = {0.f, 0.f, 0.f, 0.f, 0.f, 0.f, 0.f, 0.f};
    for (int e = beg + q; e < end; e += 4) {
        int s = ssrc[e];
        uint4 v = *reinterpret_cast<const uint4*>(feat + (size_t)s * D + l15 * 8);
        acc[0] += bf_lo(v.x); acc[1] += bf_hi(v.x);
        acc[2] += bf_lo(v.y); acc[3] += bf_hi(v.y);
        acc[4] += bf_lo(v.z); acc[5] += bf_hi(v.z);
        acc[6] += bf_lo(v.w); acc[7] += bf_hi(v.w);
    }
#pragma unroll
    for (int j = 0; j < 8; ++j) {
        acc[j] += __shfl_xor(acc[j], 16);
        acc[j] += __shfl_xor(acc[j], 32);
    }
    if (lane < 16) {
        int deg = end - beg;
        float inv = 1.0f / (float)(deg > 1 ? deg : 1);
        uint4 o;
        o.x = pack2(acc[0] * inv, acc[1] * inv);
        o.y = pack2(acc[2] * inv, acc[3] * inv);
        o.z = pack2(acc[4] * inv, acc[5] * inv);
        o.w = pack2(acc[6] * inv, acc[7] * inv);
        *reinterpret_cast<uint4*>(out + (size_t)w * D + l15 * 8) = o;
    }
}

// ---------------- MFMA dual-GEMM: out = A1*Wt[0] + A2*Wt[1] + bias [, relu] ----------------
// block: 256 thr / 4 waves; tile 64 rows x 128 cols; wave = 16 rows (M_rep=1) x 128 cols (N_rep=8)

template <bool RELU, bool OUT_BF16>
__global__ __launch_bounds__(256)
void gemm_mfma_kernel(const unsigned short* __restrict__ A1, const unsigned short* __restrict__ A2,
                      const unsigned short* __restrict__ Wt,   // [2][128n][128k-swz] bf16
                      const float* __restrict__ bias, void* __restrict__ outp, int N) {
    __shared__ unsigned short Wlds[128 * 128];   // 32 KB, swizzle baked in global layout
    __shared__ unsigned short Alds[64 * 32];     // 4 KB, per-row chunk-rotated

    const int t = threadIdx.x;
    const int w = t >> 6;
    const int lane = t & 63;
    const int l15 = lane & 15;
    const int g = lane >> 4;
    const size_t row0 = (size_t)blockIdx.x * 64;

    f32x4 acc[8];
#pragma unroll
    for (int j = 0; j < 8; ++j) acc[j] = (f32x4){0.f, 0.f, 0.f, 0.f};

    float bb[8];
#pragma unroll
    for (int j = 0; j < 8; ++j) bb[j] = bias[j * 16 + l15];

#pragma unroll
    for (int pass = 0; pass < 2; ++pass) {
        const unsigned short* __restrict__ A = pass ? A2 : A1;
        const unsigned short* __restrict__ Wp = Wt + (size_t)pass * 16384;
        // stage full 128x128 bf16 weights (linear LDS dest, swizzle pre-baked in source layout)
#pragma unroll
        for (int i = 0; i < 8; ++i) {
            int d = t + 256 * i;
            __builtin_amdgcn_global_load_lds((glb_u32_t*)(Wp + (size_t)d * 8),
                                             (lds_u32_t*)(&Wlds[d * 8]), 16, 0, 0);
        }
#pragma unroll
        for (int kiter = 0; kiter < 4; ++kiter) {
            // stage A chunk: 64 rows x 32 k; slot cs holds chunk (cs - (r>>1)) & 3
            {
                int r = t >> 2;
                int cs = t & 3;
                int c = (cs - (r >> 1)) & 3;
                const unsigned short* src = A + (row0 + r) * D + kiter * 32 + c * 8;
                __builtin_amdgcn_global_load_lds((glb_u32_t*)src,
                                                 (lds_u32_t*)(&Alds[t * 8]), 16, 0, 0);
            }
            __syncthreads();   // drains vmcnt -> A (and W) visible

            short8 a;
            {
                int r0 = w * 16 + l15;
                int cs0 = (g + (r0 >> 1)) & 3;
                a = *reinterpret_cast<const short8*>(&Alds[r0 * 32 + cs0 * 8]);
            }
#pragma unroll
            for (int j = 0; j < 8; ++j) {
                int n = j * 16 + l15;
                int cs = (kiter * 4 + g) ^ l15;
                short8 b = *reinterpret_cast<const short8*>(&Wlds[n * 128 + cs * 8]);
                acc[j] = __builtin_amdgcn_mfma_f32_16x16x32_bf16(a, b, acc[j], 0, 0, 0);
            }
            __syncthreads();   // protect Alds (and end-of-pass Wlds) overwrite
        }
    }

    // epilogue: C/D layout col=lane&15, row=(lane>>4)*4+reg
    unsigned short* outb = (unsigned short*)outp;
    float* outf = (float*)outp;
    size_t rbase = row0 + w * 16 + g * 4;
#pragma unroll
    for (int reg = 0; reg < 4; ++reg) {
        size_t row = rbase + reg;
        if (row < (size_t)N) {
#pragma unroll
            for (int j = 0; j < 8; ++j) {
                float v = acc[j][reg] + bb[j];
                if (RELU) v = v > 0.f ? v : 0.f;
                if (OUT_BF16) outb[row * D + j * 16 + l15] = f2bf(v);
                else          outf[row * D + j * 16 + l15] = v;
            }
        }
    }
}

// ---------------- launch ----------------

extern "C" void kernel_launch(void* const* d_in, const int* in_sizes, int n_in,
                              void* d_out, int out_size, void* d_ws, size_t ws_size,
                              hipStream_t stream) {
    const float* x    = (const float*)d_in[0];
    const int*   eidx = (const int*)d_in[1];
    const float* W_l1 = (const float*)d_in[2];
    const float* W_r1 = (const float*)d_in[3];
    const float* b1   = (const float*)d_in[4];
    const float* W_l2 = (const float*)d_in[5];
    const float* W_r2 = (const float*)d_in[6];
    const float* b2   = (const float*)d_in[7];
    float* out = (float*)d_out;

    const int N = in_sizes[0] / D;
    const int E = in_sizes[1] / 2;
    const int N_pad = (N + 127) & ~127;
    const int N_pad64 = (N + 63) & ~63;
    const int* src = eidx;
    const int* dst = eidx + E;

    char* ws = (char*)d_ws;
    size_t off = 0;
    auto alloc = [&](size_t bytes) {
        char* p = ws + off;
        off += (bytes + 511) & ~(size_t)511;
        return p;
    };
    int*            cnt    = (int*)alloc((size_t)N * 4);
    int*            rowptr = (int*)alloc((size_t)(N + 1) * 4);
    int*            cursor = (int*)alloc((size_t)N * 4);
    int*            ssrc   = (int*)alloc((size_t)E * 4);
    unsigned short* xb     = (unsigned short*)alloc((size_t)N_pad * D * 2);
    unsigned short* hb     = (unsigned short*)alloc((size_t)N_pad * D * 2);
    unsigned short* aggb   = (unsigned short*)alloc((size_t)N_pad * D * 2);
    unsigned short* wt     = (unsigned short*)alloc((size_t)4 * 128 * 128 * 2);

    const int total8   = N * D / 8;
    const int NB_prep  = 32 + (total8 + 255) / 256;
    const int NB_edges = (E + 255) / 256;
    const int NB_agg   = (N + 3) / 4;
    const int NB_gemm  = N_pad64 / 64;

    // prep (convert x/W, zero cnt) + CSR build
    prep_kernel<<<NB_prep, 256, 0, stream>>>(x, xb, total8, W_l1, W_r1, W_l2, W_r2, wt, cnt, N);
    count_deg_kernel<<<NB_edges, 256, 0, stream>>>(dst, cnt, E);
    scan_all_kernel<<<1, 1024, 0, stream>>>(cnt, rowptr, cursor, N, E);
    fill_kernel<<<NB_edges, 256, 0, stream>>>(src, dst, cursor, ssrc, E);

    // layer 1
    agg_kernel<<<NB_agg, 256, 0, stream>>>(xb, rowptr, ssrc, aggb, N);
    gemm_mfma_kernel<true, true><<<NB_gemm, 256, 0, stream>>>(aggb, xb, wt, b1, hb, N);

    // layer 2
    agg_kernel<<<NB_agg, 256, 0, stream>>>(hb, rowptr, ssrc, aggb, N);
    gemm_mfma_kernel<false, false><<<NB_gemm, 256, 0, stream>>>(aggb, hb, wt + 2 * 16384, b2, out, N);
}

// Round 4
// 157.126 us; speedup vs baseline: 1.6400x; 1.6400x over previous
//
#include <hip/hip_runtime.h>

#define D 128

typedef __attribute__((ext_vector_type(8))) short short8;
typedef __attribute__((ext_vector_type(4))) float f32x4;

typedef __attribute__((address_space(3))) unsigned int lds_u32_t;
typedef const __attribute__((address_space(1))) unsigned int glb_u32_t;

static __device__ __forceinline__ unsigned short f2bf(float f) {
    unsigned int u = __float_as_uint(f);
    unsigned int r = (u + 0x7fffu + ((u >> 16) & 1u)) >> 16;
    return (unsigned short)r;
}
static __device__ __forceinline__ float bf_lo(unsigned int u) {
    return __uint_as_float(u << 16);
}
static __device__ __forceinline__ float bf_hi(unsigned int u) {
    return __uint_as_float(u & 0xffff0000u);
}
static __device__ __forceinline__ unsigned int pack2(float lo, float hi) {
    return (unsigned int)f2bf(lo) | ((unsigned int)f2bf(hi) << 16);
}

// ---------------- prep: convert W (blocks 0..31), convert x + zero cnt (rest) ----------------

__global__ void prep_kernel(const float* __restrict__ x, unsigned short* __restrict__ xb,
                            int total8,
                            const float* __restrict__ W0, const float* __restrict__ W1,
                            const float* __restrict__ W2, const float* __restrict__ W3,
                            unsigned short* __restrict__ wt,
                            int* __restrict__ cnt, int N) {
    int bx = blockIdx.x;
    int t = threadIdx.x;
    if (bx < 32) {
        // W [128k][128n] fp32 -> wt bf16 [m][n][chunk-swizzled k]: chunk c at slot c ^ (n&15)
        int tid = bx * 256 + t;            // 0..8191
        int m = tid >> 11;
        const float* W = (m == 0) ? W0 : (m == 1) ? W1 : (m == 2) ? W2 : W3;
        int r = tid & 2047;
        int n = r >> 4;
        int c = r & 15;
        float f[8];
#pragma unroll
        for (int i = 0; i < 8; ++i) f[i] = W[(size_t)(c * 8 + i) * 128 + n];
        uint4 o;
        o.x = pack2(f[0], f[1]);
        o.y = pack2(f[2], f[3]);
        o.z = pack2(f[4], f[5]);
        o.w = pack2(f[6], f[7]);
        *reinterpret_cast<uint4*>(wt + (size_t)m * 16384 + n * 128 + (c ^ (n & 15)) * 8) = o;
    } else {
        int i = (bx - 32) * 256 + t;
        if (i < N) cnt[i] = 0;
        if (i < total8) {
            const float4 v0 = *reinterpret_cast<const float4*>(x + (size_t)i * 8);
            const float4 v1 = *reinterpret_cast<const float4*>(x + (size_t)i * 8 + 4);
            uint4 o;
            o.x = pack2(v0.x, v0.y);
            o.y = pack2(v0.z, v0.w);
            o.z = pack2(v1.x, v1.y);
            o.w = pack2(v1.z, v1.w);
            *reinterpret_cast<uint4*>(xb + (size_t)i * 8) = o;
        }
    }
}

// ---------------- CSR build ----------------

__global__ void count_deg_kernel(const int* __restrict__ dst, int* __restrict__ cnt, int E) {
    int e = blockIdx.x * 256 + threadIdx.x;
    if (e < E) atomicAdd(&cnt[dst[e]], 1);
}

__global__ void scan1_kernel(const int* __restrict__ cnt, int* __restrict__ rowptr,
                             int* __restrict__ bsum, int N) {
    __shared__ int tmp[256];
    int tid = threadIdx.x;
    int i = blockIdx.x * 256 + tid;
    int v = (i < N) ? cnt[i] : 0;
    tmp[tid] = v;
    __syncthreads();
    for (int off = 1; off < 256; off <<= 1) {
        int t = (tid >= off) ? tmp[tid - off] : 0;
        __syncthreads();
        tmp[tid] += t;
        __syncthreads();
    }
    if (i < N) rowptr[i] = tmp[tid] - v;            // exclusive within block
    if (tid == 255) bsum[blockIdx.x] = tmp[255];    // block total
}

__global__ void scan2_kernel(int* __restrict__ bsum, int NB) {
    __shared__ int tmp[256];
    int tid = threadIdx.x;
    int v = (tid < NB) ? bsum[tid] : 0;
    tmp[tid] = v;
    __syncthreads();
    for (int off = 1; off < 256; off <<= 1) {
        int t = (tid >= off) ? tmp[tid - off] : 0;
        __syncthreads();
        tmp[tid] += t;
        __syncthreads();
    }
    if (tid < NB) bsum[tid] = tmp[tid] - v;         // exclusive block offsets
}

__global__ void scan3_kernel(int* __restrict__ rowptr, const int* __restrict__ bsum,
                             int* __restrict__ cursor, int N, int E) {
    int i = blockIdx.x * 256 + threadIdx.x;
    if (i < N) {
        int v = rowptr[i] + bsum[blockIdx.x];
        rowptr[i] = v;
        cursor[i] = v;
    }
    if (i == 0) rowptr[N] = E;
}

__global__ void fill_kernel(const int* __restrict__ src, const int* __restrict__ dst,
                            int* __restrict__ cursor, int* __restrict__ ssrc, int E) {
    int e = blockIdx.x * 256 + threadIdx.x;
    if (e < E) {
        int d = dst[e];
        int pos = atomicAdd(&cursor[d], 1);
        ssrc[pos] = src[e];
    }
}

// ---------------- mean aggregation (bf16 in, bf16 out, fp32 accum) ----------------
// one wave per node; quarter-waves process 4 edges concurrently; 16 lanes cover 128 elems

__global__ void agg_kernel(const unsigned short* __restrict__ feat, const int* __restrict__ rowptr,
                           const int* __restrict__ ssrc, unsigned short* __restrict__ out, int N) {
    int w = (blockIdx.x * blockDim.x + threadIdx.x) >> 6;
    if (w >= N) return;
    int lane = threadIdx.x & 63;
    int q = lane >> 4;
    int l15 = lane & 15;
    int beg = rowptr[w], end = rowptr[w + 1];
    float acc[8] = {0.f, 0.f, 0.f, 0.f, 0.f, 0.f, 0.f, 0.f};
    for (int e = beg + q; e < end; e += 4) {
        int s = ssrc[e];
        uint4 v = *reinterpret_cast<const uint4*>(feat + (size_t)s * D + l15 * 8);
        acc[0] += bf_lo(v.x); acc[1] += bf_hi(v.x);
        acc[2] += bf_lo(v.y); acc[3] += bf_hi(v.y);
        acc[4] += bf_lo(v.z); acc[5] += bf_hi(v.z);
        acc[6] += bf_lo(v.w); acc[7] += bf_hi(v.w);
    }
#pragma unroll
    for (int j = 0; j < 8; ++j) {
        acc[j] += __shfl_xor(acc[j], 16);
        acc[j] += __shfl_xor(acc[j], 32);
    }
    if (lane < 16) {
        int deg = end - beg;
        float inv = 1.0f / (float)(deg > 1 ? deg : 1);
        uint4 o;
        o.x = pack2(acc[0] * inv, acc[1] * inv);
        o.y = pack2(acc[2] * inv, acc[3] * inv);
        o.z = pack2(acc[4] * inv, acc[5] * inv);
        o.w = pack2(acc[6] * inv, acc[7] * inv);
        *reinterpret_cast<uint4*>(out + (size_t)w * D + l15 * 8) = o;
    }
}

// ---------------- MFMA dual-GEMM: out = A1*Wt[0] + A2*Wt[1] + bias [, relu] ----------------
// block: 256 thr / 4 waves; tile 64 rows x 128 cols; wave = 16 rows (M_rep=1) x 128 cols (N_rep=8)

template <bool RELU, bool OUT_BF16>
__global__ __launch_bounds__(256)
void gemm_mfma_kernel(const unsigned short* __restrict__ A1, const unsigned short* __restrict__ A2,
                      const unsigned short* __restrict__ Wt,   // [2][128n][128k-swz] bf16
                      const float* __restrict__ bias, void* __restrict__ outp, int N) {
    __shared__ unsigned short Wlds[128 * 128];   // 32 KB, swizzle baked in global layout
    __shared__ unsigned short Alds[64 * 32];     // 4 KB, per-row chunk-rotated

    const int t = threadIdx.x;
    const int w = t >> 6;
    const int lane = t & 63;
    const int l15 = lane & 15;
    const int g = lane >> 4;
    const size_t row0 = (size_t)blockIdx.x * 64;

    f32x4 acc[8];
#pragma unroll
    for (int j = 0; j < 8; ++j) acc[j] = (f32x4){0.f, 0.f, 0.f, 0.f};

    float bb[8];
#pragma unroll
    for (int j = 0; j < 8; ++j) bb[j] = bias[j * 16 + l15];

#pragma unroll
    for (int pass = 0; pass < 2; ++pass) {
        const unsigned short* __restrict__ A = pass ? A2 : A1;
        const unsigned short* __restrict__ Wp = Wt + (size_t)pass * 16384;
#pragma unroll
        for (int i = 0; i < 8; ++i) {
            int d = t + 256 * i;
            __builtin_amdgcn_global_load_lds((glb_u32_t*)(Wp + (size_t)d * 8),
                                             (lds_u32_t*)(&Wlds[d * 8]), 16, 0, 0);
        }
#pragma unroll
        for (int kiter = 0; kiter < 4; ++kiter) {
            // stage A chunk: 64 rows x 32 k; slot cs holds chunk (cs - (r>>1)) & 3
            {
                int r = t >> 2;
                int cs = t & 3;
                int c = (cs - (r >> 1)) & 3;
                const unsigned short* src = A + (row0 + r) * D + kiter * 32 + c * 8;
                __builtin_amdgcn_global_load_lds((glb_u32_t*)src,
                                                 (lds_u32_t*)(&Alds[t * 8]), 16, 0, 0);
            }
            __syncthreads();   // drains vmcnt -> A (and W) visible

            short8 a;
            {
                int r0 = w * 16 + l15;
                int cs0 = (g + (r0 >> 1)) & 3;
                a = *reinterpret_cast<const short8*>(&Alds[r0 * 32 + cs0 * 8]);
            }
#pragma unroll
            for (int j = 0; j < 8; ++j) {
                int n = j * 16 + l15;
                int cs = (kiter * 4 + g) ^ l15;
                short8 b = *reinterpret_cast<const short8*>(&Wlds[n * 128 + cs * 8]);
                acc[j] = __builtin_amdgcn_mfma_f32_16x16x32_bf16(a, b, acc[j], 0, 0, 0);
            }
            __syncthreads();   // protect Alds (and end-of-pass Wlds) overwrite
        }
    }

    // epilogue: C/D layout col=lane&15, row=(lane>>4)*4+reg
    unsigned short* outb = (unsigned short*)outp;
    float* outf = (float*)outp;
    size_t rbase = row0 + w * 16 + g * 4;
#pragma unroll
    for (int reg = 0; reg < 4; ++reg) {
        size_t row = rbase + reg;
        if (row < (size_t)N) {
#pragma unroll
            for (int j = 0; j < 8; ++j) {
                float v = acc[j][reg] + bb[j];
                if (RELU) v = v > 0.f ? v : 0.f;
                if (OUT_BF16) outb[row * D + j * 16 + l15] = f2bf(v);
                else          outf[row * D + j * 16 + l15] = v;
            }
        }
    }
}

// ---------------- launch ----------------

extern "C" void kernel_launch(void* const* d_in, const int* in_sizes, int n_in,
                              void* d_out, int out_size, void* d_ws, size_t ws_size,
                              hipStream_t stream) {
    const float* x    = (const float*)d_in[0];
    const int*   eidx = (const int*)d_in[1];
    const float* W_l1 = (const float*)d_in[2];
    const float* W_r1 = (const float*)d_in[3];
    const float* b1   = (const float*)d_in[4];
    const float* W_l2 = (const float*)d_in[5];
    const float* W_r2 = (const float*)d_in[6];
    const float* b2   = (const float*)d_in[7];
    float* out = (float*)d_out;

    const int N = in_sizes[0] / D;
    const int E = in_sizes[1] / 2;
    const int N_pad = (N + 127) & ~127;
    const int N_pad64 = (N + 63) & ~63;
    const int* src = eidx;
    const int* dst = eidx + E;

    char* ws = (char*)d_ws;
    size_t off = 0;
    auto alloc = [&](size_t bytes) {
        char* p = ws + off;
        off += (bytes + 511) & ~(size_t)511;
        return p;
    };
    int*            cnt    = (int*)alloc((size_t)N * 4);
    int*            rowptr = (int*)alloc((size_t)(N + 1) * 4);
    int*            cursor = (int*)alloc((size_t)N * 4);
    int*            bsum   = (int*)alloc(1024);
    int*            ssrc   = (int*)alloc((size_t)E * 4);
    unsigned short* xb     = (unsigned short*)alloc((size_t)N_pad * D * 2);
    unsigned short* hb     = (unsigned short*)alloc((size_t)N_pad * D * 2);
    unsigned short* aggb   = (unsigned short*)alloc((size_t)N_pad * D * 2);
    unsigned short* wt     = (unsigned short*)alloc((size_t)4 * 128 * 128 * 2);

    const int total8   = N * D / 8;
    const int NB_prep  = 32 + (total8 + 255) / 256;
    const int NB_edges = (E + 255) / 256;
    const int NB_nodes = (N + 255) / 256;   // 196 <= 256, fits scan2's single block
    const int NB_agg   = (N + 3) / 4;
    const int NB_gemm  = N_pad64 / 64;

    // prep (convert x/W, zero cnt) + CSR build
    prep_kernel<<<NB_prep, 256, 0, stream>>>(x, xb, total8, W_l1, W_r1, W_l2, W_r2, wt, cnt, N);
    count_deg_kernel<<<NB_edges, 256, 0, stream>>>(dst, cnt, E);
    scan1_kernel<<<NB_nodes, 256, 0, stream>>>(cnt, rowptr, bsum, N);
    scan2_kernel<<<1, 256, 0, stream>>>(bsum, NB_nodes);
    scan3_kernel<<<NB_nodes, 256, 0, stream>>>(rowptr, bsum, cursor, N, E);
    fill_kernel<<<NB_edges, 256, 0, stream>>>(src, dst, cursor, ssrc, E);

    // layer 1
    agg_kernel<<<NB_agg, 256, 0, stream>>>(xb, rowptr, ssrc, aggb, N);
    gemm_mfma_kernel<true, true><<<NB_gemm, 256, 0, stream>>>(aggb, xb, wt, b1, hb, N);

    // layer 2
    agg_kernel<<<NB_agg, 256, 0, stream>>>(hb, rowptr, ssrc, aggb, N);
    gemm_mfma_kernel<false, false><<<NB_gemm, 256, 0, stream>>>(aggb, hb, wt + 2 * 16384, b2, out, N);
}